// Round 7
// baseline (62.620 us; speedup 1.0000x reference)
//
#include <hip/hip_runtime.h>

#define NUM_IND 1000
#define ROWPAD  40   // floats per padded LDS row (160 B): bank base = 8*(id&3)

typedef float f4 __attribute__((ext_vector_type(4)));

// ONE fused kernel, 1024 threads x 256 blocks (1 block/CU, 16 waves).
// Phase 1: build padded 1000x40 table in LDS (thread t -> industry t).
// Phase 2: BLOCK-COOPERATIVE gather. Block b owns ONE contiguous 1 MB span
// (mpb=128 macros). Wave w takes macros b*mpb + w, +16, +32, ... so at any
// instant the block's 16 waves write 16 ADJACENT 8 KB macros of one 128 KB
// window that advances monotonically -> each CU presents ~one sequential
// DRAM write stream (fill-kernel regime) instead of 16 scattered ones.
// Idx: 64 values per macro in one coalesced 256 B load, prefetched one
// macro ahead (clamped, branchless), distributed by __shfl.
__global__ __launch_bounds__(1024) void fused_encoder_kernel(
    const int*   __restrict__ idx,   // [B]
    const float* __restrict__ vars,  // [1000,8]
    const float* __restrict__ W1,    // [8,16]
    const float* __restrict__ b1,    // [16]
    const float* __restrict__ W2,    // [16,32]
    const float* __restrict__ b2,    // [32]
    const float* __restrict__ emb,   // [1000,32]
    f4*          __restrict__ out4,  // [B*8]
    int nmacros,                     // total4 / 512
    int mpb,                         // macros per block
    int total4)                      // B*8
{
    __shared__ __align__(16) float table[NUM_IND * ROWPAD];  // 160,000 B

    const int tid  = threadIdx.x;
    const int lane = tid & 63;
    const int wid  = tid >> 6;                    // 0..15

    const int mbeg = blockIdx.x * mpb + wid;      // this wave's first macro
    const int mend = min(blockIdx.x * mpb + mpb, nmacros);

    // ---- prefetch first macro's idx BEFORE the build (hides under MLP) ----
    const int last = nmacros - 1;
    int a = idx[min(mbeg, last) * 64 + lane];

    // ---- build phase: thread t computes industry t's 32 outputs ----
    if (tid < NUM_IND) {
        float v[8];
#pragma unroll
        for (int k = 0; k < 8; ++k) v[k] = vars[tid * 8 + k];

        float h[16];
#pragma unroll
        for (int j = 0; j < 16; ++j) {
            float acc = b1[j];
#pragma unroll
            for (int k = 0; k < 8; ++k) acc = fmaf(v[k], W1[k * 16 + j], acc);
            h[j] = fmaxf(acc, 0.0f);
        }

        const f4* embrow = (const f4*)(emb + tid * 32);
        f4* tabrow = (f4*)(table + tid * ROWPAD);
#pragma unroll
        for (int r = 0; r < 8; ++r) {             // 8 f4 chunks of 32 outputs
            const f4 e = embrow[r];
            f4 o;
#pragma unroll
            for (int q = 0; q < 4; ++q) {
                const int j = r * 4 + q;
                float acc = b2[j];
#pragma unroll
                for (int k = 0; k < 16; ++k) acc = fmaf(h[k], W2[k * 32 + j], acc);
                o[q] = acc + 0.1f * e[q];
            }
            tabrow[r] = o;
        }
    }
    __syncthreads();

    const f4* tab4 = (const f4*)table;            // padded: row stride 10 f4

    // ---- block-cooperative macro loop: wave stride 16 inside block span ----
    for (int m = mbeg; m < mend; m += 16) {
        // branchless clamped prefetch of next macro's idx
        const int a_next = idx[min(m + 16, last) * 64 + lane];

        const int base = m * 512 + lane;
#pragma unroll
        for (int c = 0; c < 8; ++c) {
            // lane serves chunk c*64+lane -> example 8c + (lane>>3) of macro
            const int id = __shfl(a, 8 * c + (lane >> 3), 64);
            out4[base + c * 64] = tab4[id * (ROWPAD / 4) + (lane & 7)];
        }
        a = a_next;
    }

    // ---- generic tail (elements beyond full macros); empty for B = 2^21 ----
    if (blockIdx.x == 0 && tid < 64) {
        for (int g = nmacros * 512 + lane; g < total4; g += 64) {
            const int id = idx[g >> 3];
            out4[g] = tab4[id * (ROWPAD / 4) + (g & 7)];
        }
    }
}

extern "C" void kernel_launch(void* const* d_in, const int* in_sizes, int n_in,
                              void* d_out, int out_size, void* d_ws, size_t ws_size,
                              hipStream_t stream) {
    const int*   idx  = (const int*)  d_in[0];  // [B] int32
    const float* vars = (const float*)d_in[1];  // [1000,8]
    const float* W1   = (const float*)d_in[2];  // [8,16]
    const float* b1   = (const float*)d_in[3];  // [16]
    const float* W2   = (const float*)d_in[4];  // [16,32]
    const float* b2   = (const float*)d_in[5];  // [32]
    const float* emb  = (const float*)d_in[6];  // [1000,32]

    f4* out4 = (f4*)d_out;                      // [B*8] 16B chunks
    const int B = in_sizes[0];
    const int total4  = B * 8;                  // 16,777,216 for B=2^21
    const int nmacros = total4 / 512;           // 32,768

    const int blocks = 256, threads = 1024;
    const int mpb = (nmacros + blocks - 1) / blocks;   // 128 for B=2^21

    fused_encoder_kernel<<<blocks, threads, 0, stream>>>(idx, vars, W1, b1, W2,
                                                         b2, emb, out4,
                                                         nmacros, mpb, total4);
}

// Round 8
// 51.323 us; speedup vs baseline: 1.2201x; 1.2201x over previous
//
#include <hip/hip_runtime.h>

#define NUM_IND 1000
#define ROWPAD  40   // floats per padded LDS row (160 B): bank base = 8*(id&3)
#define MPW     8    // macros per wave (contiguous 64 KB span)

typedef float f4 __attribute__((ext_vector_type(4)));

// ONE fused kernel, 1024 threads x 256 blocks (1 block/CU, 16 waves).
// Phase 0: each wave loads ALL idx for its contiguous 8-macro (64 KB) span
//          upfront: 8 coalesced 256 B loads -> 8 per-lane registers. These
//          complete under the build phase's MLP.
// Phase 1: build padded 1000x40 table in LDS (thread t -> industry t).
// Phase 2: ZERO-LOAD gather: fully unrolled 8x8 shfl -> ds_read -> store.
//          Each wave emits a pure, monotonically-ascending 64 KB write
//          stream (fill-kernel regime: no read/write turnaround, no waits).
__global__ __launch_bounds__(1024) void fused_encoder_kernel(
    const int*   __restrict__ idx,   // [B]
    const float* __restrict__ vars,  // [1000,8]
    const float* __restrict__ W1,    // [8,16]
    const float* __restrict__ b1,    // [16]
    const float* __restrict__ W2,    // [16,32]
    const float* __restrict__ b2,    // [32]
    const float* __restrict__ emb,   // [1000,32]
    f4*          __restrict__ out4,  // [B*8]
    int nmacros,                     // total4 / 512
    int total4)                      // B*8
{
    __shared__ __align__(16) float table[NUM_IND * ROWPAD];  // 160,000 B

    const int tid  = threadIdx.x;
    const int lane = tid & 63;
    const int wave = blockIdx.x * (blockDim.x >> 6) + (tid >> 6);
    const int mbeg = wave * MPW;                  // contiguous span start
    const int last = nmacros - 1;

    // ---- phase 0: all idx for this wave's span, before the build ----
    int a[MPW];
#pragma unroll
    for (int q = 0; q < MPW; ++q)
        a[q] = idx[min(mbeg + q, last) * 64 + lane];   // clamped, branchless

    // ---- phase 1: thread t computes industry t's 32 outputs ----
    if (tid < NUM_IND) {
        float v[8];
#pragma unroll
        for (int k = 0; k < 8; ++k) v[k] = vars[tid * 8 + k];

        float h[16];
#pragma unroll
        for (int j = 0; j < 16; ++j) {
            float acc = b1[j];
#pragma unroll
            for (int k = 0; k < 8; ++k) acc = fmaf(v[k], W1[k * 16 + j], acc);
            h[j] = fmaxf(acc, 0.0f);
        }

        const f4* embrow = (const f4*)(emb + tid * 32);
        f4* tabrow = (f4*)(table + tid * ROWPAD);
#pragma unroll
        for (int r = 0; r < 8; ++r) {             // 8 f4 chunks of 32 outputs
            const f4 e = embrow[r];
            f4 o;
#pragma unroll
            for (int q = 0; q < 4; ++q) {
                const int j = r * 4 + q;
                float acc = b2[j];
#pragma unroll
                for (int k = 0; k < 16; ++k) acc = fmaf(h[k], W2[k * 32 + j], acc);
                o[q] = acc + 0.1f * e[q];
            }
            tabrow[r] = o;
        }
    }
    __syncthreads();

    const f4* tab4 = (const f4*)table;            // padded: row stride 10 f4

    // ---- phase 2: zero-load gather over the wave's contiguous span ----
    if (mbeg + MPW <= nmacros) {                  // full span (common case)
#pragma unroll
        for (int q = 0; q < MPW; ++q) {
            const int base = (mbeg + q) * 512 + lane;
#pragma unroll
            for (int c = 0; c < 8; ++c) {
                // lane serves chunk c*64+lane -> example 8c+(lane>>3)
                const int id = __shfl(a[q], 8 * c + (lane >> 3), 64);
                out4[base + c * 64] = tab4[id * (ROWPAD / 4) + (lane & 7)];
            }
        }
    } else {                                      // partial span (generic B)
#pragma unroll
        for (int q = 0; q < MPW; ++q) {
            if (mbeg + q < nmacros) {
                const int base = (mbeg + q) * 512 + lane;
#pragma unroll
                for (int c = 0; c < 8; ++c) {
                    const int id = __shfl(a[q], 8 * c + (lane >> 3), 64);
                    out4[base + c * 64] = tab4[id * (ROWPAD / 4) + (lane & 7)];
                }
            }
        }
    }

    // ---- generic tail (elements beyond full macros); empty for B = 2^21 ----
    if (blockIdx.x == 0 && tid < 64) {
        for (int g = nmacros * 512 + lane; g < total4; g += 64) {
            const int id = idx[g >> 3];
            out4[g] = tab4[id * (ROWPAD / 4) + (g & 7)];
        }
    }
}

extern "C" void kernel_launch(void* const* d_in, const int* in_sizes, int n_in,
                              void* d_out, int out_size, void* d_ws, size_t ws_size,
                              hipStream_t stream) {
    const int*   idx  = (const int*)  d_in[0];  // [B] int32
    const float* vars = (const float*)d_in[1];  // [1000,8]
    const float* W1   = (const float*)d_in[2];  // [8,16]
    const float* b1   = (const float*)d_in[3];  // [16]
    const float* W2   = (const float*)d_in[4];  // [16,32]
    const float* b2   = (const float*)d_in[5];  // [32]
    const float* emb  = (const float*)d_in[6];  // [1000,32]

    f4* out4 = (f4*)d_out;                      // [B*8] 16B chunks
    const int B = in_sizes[0];
    const int total4  = B * 8;                  // 16,777,216 for B=2^21
    const int nmacros = total4 / 512;           // 32,768

    // 256 blocks x 1024 threads = 4096 waves x 8 macros = 32,768 macros.
    fused_encoder_kernel<<<256, 1024, 0, stream>>>(idx, vars, W1, b1, W2, b2,
                                                   emb, out4, nmacros, total4);
}